// Round 7
// baseline (282.507 us; speedup 1.0000x reference)
//
#include <hip/hip_runtime.h>

#define NROWS 16384
#define NC    2048
#define NB    1024          // bins per row (one wave's private LDS region)
#define NT    256           // 4 waves/block, ONE ROW PER WAVE, no __syncthreads
#define RPB   4             // rows per block
#define EPL   32            // elements per lane (NC/64)
#define BPL   16            // bins per lane  (NB/64)

// Wave-private swizzled bin layout: bin b at word (b&15)*64 + (b>>4).
// Lane L owns bins 16L..16L+15 (contiguous in scan order) at words j*64+L ->
// stride-1 across lanes in structured phases (2 lanes/bank = free, m136).
// Random atomics: bank = (b>>4) & 31, uniform for CDF-uniform bins.
__device__ __forceinline__ int SWZ(int b) { return ((b & (BPL - 1)) << 6) | (b >> 4); }

// Per wave: zero -> packed hist atomics -> wave-local packed exclusive scan
// (shfl, no LDS round-trip) -> rank atomics (old value = (global_rank<<16)|
// pos_rank per R5) -> shuffle reduce -> store. Wave64 is implicitly
// synchronous; __threadfence_block() = lgkmcnt drain orders the LDS phases.
__global__ __launch_bounds__(NT, 6) void lrap_rows(const float* __restrict__ preds,
                                                   const float* __restrict__ labels,
                                                   float* __restrict__ rowsc)
{
    __shared__ unsigned int bins_all[RPB * NB];

    const int t    = threadIdx.x;
    const int lane = t & 63;
    const int wid  = t >> 6;
    const int row  = blockIdx.x * RPB + wid;

    unsigned int* bins = bins_all + wid * NB;

    const float* prow = preds  + (size_t)row * NC;
    const float* lrow = labels + (size_t)row * NC;

    // ---- coalesced loads: 8+8 float4 per lane, all issued up front ----
    float4 p[8], l[8];
    #pragma unroll
    for (int c = 0; c < 8; ++c) p[c] = ((const float4*)prow)[(c << 6) + lane];
    #pragma unroll
    for (int c = 0; c < 8; ++c) l[c] = ((const float4*)lrow)[(c << 6) + lane];

    // ---- zero my wave's bins (conflict-free) ----
    #pragma unroll
    for (int j = 0; j < BPL; ++j) bins[(j << 6) + lane] = 0u;
    __threadfence_block();

    // ---- bin via logistic CDF (monotone decr), packed hist; labels -> bitmask ----
    unsigned int lmask = 0u;
    unsigned int bpack[EPL / 2];
    #pragma unroll
    for (int c = 0; c < 8; ++c) {
        float pvq[4] = {p[c].x, p[c].y, p[c].z, p[c].w};
        float lvq[4] = {l[c].x, l[c].y, l[c].z, l[c].w};
        #pragma unroll
        for (int q = 0; q < 4; ++q) {
            int e = (c << 2) + q;
            unsigned int lb = (lvq[q] != 0.0f) ? 1u : 0u;
            lmask |= lb << e;
            float ex = __expf(1.702f * pvq[q]);
            float tt = (float)NB * __builtin_amdgcn_rcpf(1.0f + ex);
            int b = (int)tt;
            b = b < 0 ? 0 : (b > NB - 1 ? NB - 1 : b);
            if (q & 1) bpack[e >> 1] |= (unsigned int)b << 16;
            else       bpack[e >> 1]  = (unsigned int)b;
            atomicAdd(&bins[SWZ(b)], 0x10000u + lb);   // all+=1 (hi), pos+=lb (lo)
        }
    }
    __threadfence_block();

    // ---- wave-local packed exclusive scan over 1024 bins (pure shfl) ----
    unsigned int run[BPL];
    unsigned int s = 0;
    #pragma unroll
    for (int j = 0; j < BPL; ++j) {
        unsigned int h = bins[(j << 6) + lane];
        run[j] = s; s += h;
    }
    unsigned int x = s;
    #pragma unroll
    for (int d = 1; d < 64; d <<= 1) {
        unsigned int y = __shfl_up(x, (unsigned)d, 64);
        if (lane >= d) x += y;
    }
    unsigned int tot  = __shfl(x, 63, 64);   // (2048<<16) | k for this row
    unsigned int base = x - s;
    #pragma unroll
    for (int j = 0; j < BPL; ++j) bins[(j << 6) + lane] = base + run[j];
    __threadfence_block();

    // ---- rank: one packed atomic per element; term from returned old value ----
    float part = 0.0f;
    #pragma unroll
    for (int e = 0; e < EPL; ++e) {
        unsigned int b  = (bpack[e >> 1] >> ((e & 1) << 4)) & 0xFFFFu;
        unsigned int lb = (lmask >> e) & 1u;
        unsigned int old = atomicAdd(&bins[SWZ((int)b)], 0x10000u + lb);
        if (lb) {
            float jv = (float)((old & 0xFFFFu) + 1u);   // 1-idx rank among positives
            float rv = (float)((old >> 16) + 1u);       // 1-idx global rank
            part += jv * __builtin_amdgcn_rcpf(rv);
        }
    }

    // ---- wave reduce, store per-row score ----
    #pragma unroll
    for (int d = 32; d >= 1; d >>= 1) part += __shfl_down(part, (unsigned)d, 64);
    if (lane == 0) {
        unsigned int k = tot & 0xFFFFu;
        rowsc[row] = (k > 0u) ? (part / (float)k) : 0.0f;
    }
}

__global__ __launch_bounds__(1024) void mean_reduce(const float* __restrict__ v,
                                                    float* __restrict__ out)
{
    __shared__ float ws[16];
    int t = threadIdx.x;
    float s = 0.f;
    for (int i = t; i < NROWS; i += 1024) s += v[i];
    int lane = t & 63, wid = t >> 6;
    #pragma unroll
    for (int d = 32; d >= 1; d >>= 1) s += __shfl_down(s, (unsigned)d, 64);
    if (lane == 0) ws[wid] = s;
    __syncthreads();
    if (t == 0) {
        float a = 0.f;
        for (int w = 0; w < 16; ++w) a += ws[w];
        out[0] = a / (float)NROWS;
    }
}

extern "C" void kernel_launch(void* const* d_in, const int* in_sizes, int n_in,
                              void* d_out, int out_size, void* d_ws, size_t ws_size,
                              hipStream_t stream)
{
    const float* preds  = (const float*)d_in[0];
    const float* labels = (const float*)d_in[1];
    float* rowsc = (float*)d_ws;   // NROWS floats of scratch

    lrap_rows<<<NROWS / RPB, NT, 0, stream>>>(preds, labels, rowsc);
    mean_reduce<<<1, 1024, 0, stream>>>(rowsc, (float*)d_out);
}